// Round 3
// baseline (839.959 us; speedup 1.0000x reference)
//
#include <hip/hip_runtime.h>
#include <hip/hip_cooperative_groups.h>
#include <math.h>

namespace cg = cooperative_groups;

#define N_NODES 4096
#define HIDN 128
#define MAXNZ 128
#define CGRID 512
#define NTHR 512

typedef float v4f __attribute__((ext_vector_type(4)));
typedef _Float16 h2 __attribute__((ext_vector_type(2)));
typedef _Float16 h8 __attribute__((ext_vector_type(8)));

__device__ __forceinline__ float fsig(float x) { return 1.0f / (1.0f + __expf(-x)); }
__device__ __forceinline__ float ftanh_(float x) { return 1.0f - 2.0f / (__expf(2.0f * x) + 1.0f); }

// ---------------------------------------------------------------------------
// Phase bodies (shared between the cooperative mega-kernel and the fallback
// 3-kernel path). LDS is passed as pointers into a per-kernel arena.
// ---------------------------------------------------------------------------

// conv1d + z precompute for one conv-block cb in [0,128). Needs 2 KB LDS (dl).
__device__ __forceinline__ void convz_body(
        int cb, int tid, const float* __restrict__ x,
        const float* __restrict__ conv_w, const float* __restrict__ conv_b,
        const float* __restrict__ w_ih, const float* __restrict__ b_ih,
        const float* __restrict__ b_hh, float* __restrict__ z3,
        float* dl /* 4*128 floats */) {
    const int b = cb >> 5;
    const int t0 = (cb & 31) * 4;
    const int tsub = tid >> 7;
    const int h = tid & 127;
    const int t = t0 + tsub;                       // timestep 0..127
    {
        const float* xb = x + ((size_t)b * N_NODES + (N_NODES - HIDN)) * HIDN;
        const float* w = conv_w + (size_t)t * HIDN * 3;
        float a0 = conv_b[t], a1 = 0.0f, a2 = 0.0f, a3 = 0.0f;
        #pragma unroll 4
        for (int i = 0; i < HIDN; i += 4) {
            const float* xr0 = xb + (size_t)i * HIDN;
            #pragma unroll
            for (int s = 0; s < 4; ++s) {
                const float* xr = xr0 + s * HIDN;
                float w0 = w[(i + s) * 3 + 0], w1 = w[(i + s) * 3 + 1], w2 = w[(i + s) * 3 + 2];
                float left  = (h > 0)   ? xr[h - 1] : 0.0f;
                float mid   = xr[h];
                float right = (h < 127) ? xr[h + 1] : 0.0f;
                if (s == 0)      a0 += left * w0 + mid * w1 + right * w2;
                else if (s == 1) a1 += left * w0 + mid * w1 + right * w2;
                else if (s == 2) a2 += left * w0 + mid * w1 + right * w2;
                else             a3 += left * w0 + mid * w1 + right * w2;
            }
        }
        dl[tsub * HIDN + h] = (a0 + a1) + (a2 + a3);
    }
    __syncthreads();
    // ---- z phase: thread = u = gate*128 + cell; 4 timesteps per thread ----
    const int u = tid;
    const int qg = u >> 7;                         // gate
    const int m  = u & 127;                        // cell
    const float4* wr = (const float4*)(w_ih + (size_t)u * HIDN);
    float bias = b_ih[u] + b_hh[u];
    float acc0 = bias, acc1 = bias, acc2 = bias, acc3 = bias;
    #pragma unroll
    for (int half = 0; half < 2; ++half) {
        float4 wv[16];
        #pragma unroll
        for (int j = 0; j < 16; ++j) wv[j] = wr[half * 16 + j];
        const float4* d0 = (const float4*)(dl + 0 * HIDN) + half * 16;
        const float4* d1 = (const float4*)(dl + 1 * HIDN) + half * 16;
        const float4* d2 = (const float4*)(dl + 2 * HIDN) + half * 16;
        const float4* d3 = (const float4*)(dl + 3 * HIDN) + half * 16;
        #pragma unroll
        for (int j = 0; j < 16; ++j) {
            float4 wj = wv[j];
            float4 v0 = d0[j], v1 = d1[j], v2 = d2[j], v3 = d3[j];
            acc0 += wj.x * v0.x + wj.y * v0.y + wj.z * v0.z + wj.w * v0.w;
            acc1 += wj.x * v1.x + wj.y * v1.y + wj.z * v1.z + wj.w * v1.w;
            acc2 += wj.x * v2.x + wj.y * v2.y + wj.z * v2.z + wj.w * v2.w;
            acc3 += wj.x * v3.x + wj.y * v3.y + wj.z * v3.z + wj.w * v3.w;
        }
    }
    float* zb = z3 + (size_t)b * HIDN * HIDN * 4;
    zb[((size_t)(t0 + 0) * 128 + m) * 4 + qg] = acc0;
    zb[((size_t)(t0 + 1) * 128 + m) * 4 + qg] = acc1;
    zb[((size_t)(t0 + 2) * 128 + m) * 4 + qg] = acc2;
    zb[((size_t)(t0 + 3) * 128 + m) * 4 + qg] = acc3;
}

// A-scan of one row r by one wave. sidx_w = 128 ints of LDS private to wave.
__device__ __forceinline__ void ascan_row(
        int r, int lane, const float* __restrict__ A, float* __restrict__ d_inv,
        int* __restrict__ cnt, int* __restrict__ idx, int* sidx_w) {
    const v4f* row = (const v4f*)(A + (size_t)r * N_NODES);
    const unsigned long long below = (1ull << lane) - 1ull;
    int cbase = 0;
    v4f cur[4], nxt[4];
    #pragma unroll
    for (int j = 0; j < 4; ++j) cur[j] = row[j * 64 + lane];
#define PROC1(c, col)                                                         \
    {                                                                         \
        bool nz = ((c) != 0.0f);                                              \
        unsigned long long mm = __ballot(nz);                                 \
        if (mm) {                                                             \
            if (nz) {                                                         \
                int p_ = cbase + __popcll(mm & below);                        \
                if (p_ < MAXNZ) sidx_w[p_] = (col);                           \
            }                                                                 \
            cbase += __popcll(mm);                                            \
        }                                                                     \
    }
    #pragma unroll
    for (int g = 0; g < 4; ++g) {
        if (g < 3) {
            #pragma unroll
            for (int j = 0; j < 4; ++j) nxt[j] = row[(g + 1) * 256 + j * 64 + lane];
        }
        #pragma unroll
        for (int j = 0; j < 4; ++j) {
            int col0 = ((g * 4 + j) * 64 + lane) * 4;
            PROC1(cur[j].x, col0 + 0);
            PROC1(cur[j].y, col0 + 1);
            PROC1(cur[j].z, col0 + 2);
            PROC1(cur[j].w, col0 + 3);
        }
        #pragma unroll
        for (int j = 0; j < 4; ++j) cur[j] = nxt[j];
    }
#undef PROC1
    int cnt_r = (cbase < MAXNZ) ? cbase : MAXNZ;
    for (int k = lane; k < cnt_r; k += 64)
        idx[r * MAXNZ + k] = sidx_w[k];
    if (lane == 0) {
        cnt[r] = cnt_r;
        d_inv[r] = rsqrtf((float)(cbase + 1));
    }
}

// LSTM for batch b, full 512-thread block. zl = 32 KB, hb = 512 B of LDS.
// thread = (cell m = t>>2, k-quarter q = t&3); w2 = 64 VGPR of f16 weights,
// H0-H3 = 16 VGPR h-quarter, total ~115 VGPR -> fits the 128 cap, no spill.
__device__ __forceinline__ void lstm_body(
        int b, int t, const float* __restrict__ z3, const float* __restrict__ w_hh,
        float* __restrict__ lw, float4* zl, _Float16* hb) {
    const int m = t >> 2;                          // cell 0..127
    const int q = t & 3;                           // k-quarter 0..3
    h2 w2[4][16];
    #pragma unroll
    for (int g = 0; g < 4; ++g) {
        const float4* wr = (const float4*)(w_hh + ((size_t)(g * HIDN + m)) * HIDN + q * 32);
        #pragma unroll
        for (int j4 = 0; j4 < 8; ++j4) {
            float4 wv = wr[j4];
            w2[g][2 * j4 + 0] = h2{(_Float16)wv.x, (_Float16)wv.y};
            w2[g][2 * j4 + 1] = h2{(_Float16)wv.z, (_Float16)wv.w};
        }
    }
    float c = 0.0f;
    if (t < 64) ((h2*)hb)[t] = h2{(_Float16)0.0f, (_Float16)0.0f};
    const float4* zsrc = (const float4*)z3 + (size_t)b * 16384;
    float* lwb = lw + (size_t)b * HIDN * HIDN + m;
    float hist[4];
    for (int ch = 0; ch < 8; ++ch) {
        // ---- stage chunk (all 8 waves): 32 KB straight copy ----
        const float4* src = zsrc + ch * 2048;
        #pragma unroll
        for (int k = 0; k < 4; ++k)
            zl[t + 512 * k] = src[t + 512 * k];
        __syncthreads();
        #pragma unroll
        for (int si = 0; si < 16; ++si) {
            const int s = ch * 16 + si;
            const h8* hp = ((const h8*)(hb + (size_t)(s & 1) * HIDN)) + q * 4;
            h8 H0 = hp[0], H1 = hp[1], H2 = hp[2], H3 = hp[3];
            float4 zv = zl[si * 128 + m];          // broadcast b128
            float a0 = 0.f, a1 = 0.f, a2 = 0.f, a3 = 0.f;
            #pragma unroll
            for (int j = 0; j < 16; ++j) {
                h2 hj = (j < 4)  ? ((const h2*)&H0)[j]
                      : (j < 8)  ? ((const h2*)&H1)[j - 4]
                      : (j < 12) ? ((const h2*)&H2)[j - 8]
                                 : ((const h2*)&H3)[j - 12];
                a0 = __builtin_amdgcn_fdot2(w2[0][j], hj, a0, false);
                a1 = __builtin_amdgcn_fdot2(w2[1][j], hj, a1, false);
                a2 = __builtin_amdgcn_fdot2(w2[2][j], hj, a2, false);
                a3 = __builtin_amdgcn_fdot2(w2[3][j], hj, a3, false);
            }
            // butterfly across the 4 k-quarters (lanes t^1, t^2)
            a0 += __shfl_xor(a0, 1); a0 += __shfl_xor(a0, 2);
            a1 += __shfl_xor(a1, 1); a1 += __shfl_xor(a1, 2);
            a2 += __shfl_xor(a2, 1); a2 += __shfl_xor(a2, 2);
            a3 += __shfl_xor(a3, 1); a3 += __shfl_xor(a3, 2);
            float zi = a0 + zv.x;
            float zf = a1 + zv.y;
            float zg = a2 + zv.z;
            float zo = a3 + zv.w;
            float ig = fsig(zi);
            float fg = fsig(zf);
            float gg = ftanh_(zg);
            float og = fsig(zo);
            c = fg * c + ig * gg;                  // identical in all 4 quartet lanes
            float hn = og * ftanh_(c);
            if (q == (si & 3)) hist[si >> 2] = hn; // each quartet lane keeps 4 steps
            if (q == 0) hb[(size_t)((s + 1) & 1) * HIDN + m] = (_Float16)hn;
            __syncthreads();
        }
        // chunk-end lw store (f32, full precision), coalesced per q-group
        #pragma unroll
        for (int j = 0; j < 4; ++j)
            lwb[(size_t)(ch * 16 + q + 4 * j) * HIDN] = hist[j];
    }
}

// gather of one row r by one wave; d_inv read from global (L2/L3-resident,
// wave-uniform broadcast loads) so no LDS staging is needed.
__device__ __forceinline__ void gather_row(
        int r, int lane, const float* __restrict__ x,
        const float* __restrict__ d_inv, const int* __restrict__ cnt,
        const int* __restrict__ idx, float* __restrict__ agg) {
    const int b = r >> 12;
    const int i = r & 4095;
    const float* dv = d_inv + (b << 12);
    const float2* xb = (const float2*)(x + (size_t)b * N_NODES * HIDN);
    const int* irow = idx + r * MAXNZ;
    const int n = cnt[r];
    float ax = 0.0f, ay = 0.0f;
    int k = 0;
    for (; k + 8 <= n; k += 8) {
        int4 j0 = *(const int4*)&irow[k];
        int4 j1 = *(const int4*)&irow[k + 4];
        float2 v0 = xb[(size_t)j0.x * 64 + lane];
        float2 v1 = xb[(size_t)j0.y * 64 + lane];
        float2 v2 = xb[(size_t)j0.z * 64 + lane];
        float2 v3 = xb[(size_t)j0.w * 64 + lane];
        float2 v4 = xb[(size_t)j1.x * 64 + lane];
        float2 v5 = xb[(size_t)j1.y * 64 + lane];
        float2 v6 = xb[(size_t)j1.z * 64 + lane];
        float2 v7 = xb[(size_t)j1.w * 64 + lane];
        float d0 = dv[j0.x], d1 = dv[j0.y], d2 = dv[j0.z], d3 = dv[j0.w];
        float d4 = dv[j1.x], d5 = dv[j1.y], d6 = dv[j1.z], d7 = dv[j1.w];
        ax += d0 * v0.x + d1 * v1.x + d2 * v2.x + d3 * v3.x
            + d4 * v4.x + d5 * v5.x + d6 * v6.x + d7 * v7.x;
        ay += d0 * v0.y + d1 * v1.y + d2 * v2.y + d3 * v3.y
            + d4 * v4.y + d5 * v5.y + d6 * v6.y + d7 * v7.y;
    }
    for (; k < n; ++k) {
        int j = irow[k];
        float dj = dv[j];
        float2 v = xb[(size_t)j * 64 + lane];
        ax += dj * v.x;
        ay += dj * v.y;
    }
    float di = dv[i];
    float2 vi = xb[(size_t)i * 64 + lane];
    float2 o2;
    o2.x = di * (ax + di * vi.x);
    o2.y = di * (ay + di * vi.y);
    ((float2*)(agg + (size_t)r * HIDN))[lane] = o2;
}

// outmm for block bb in [0,256): 64 rows, 512 threads (1 row x 16 cols each).
// lw_lds = 64 KB LDS.
__device__ __forceinline__ void outmm_body(
        int bb, int tid, const float* __restrict__ agg,
        const float* __restrict__ lw, float* __restrict__ out, float* lw_lds) {
    const int i0 = bb * 64;
    const int b = i0 >> 12;
    const float4* lwg = (const float4*)(lw + (size_t)b * HIDN * HIDN);
    float4* lds4 = (float4*)lw_lds;
    for (int v = tid; v < HIDN * HIDN / 4; v += NTHR) lds4[v] = lwg[v];
    __syncthreads();
    const int r0 = i0 + (tid >> 3);
    const int u0 = (tid & 7) * 16;
    const float4* a4 = (const float4*)agg;
    float4 acc[4];
    #pragma unroll
    for (int cc = 0; cc < 4; ++cc) acc[cc] = make_float4(0.f, 0.f, 0.f, 0.f);
    for (int f4 = 0; f4 < 32; ++f4) {
        float4 a0 = a4[(size_t)r0 * 32 + f4];
        #pragma unroll
        for (int ff = 0; ff < 4; ++ff) {
            float af0 = (ff == 0) ? a0.x : (ff == 1) ? a0.y : (ff == 2) ? a0.z : a0.w;
            const float4* wrow = (const float4*)(lw_lds + (f4 * 4 + ff) * HIDN + u0);
            #pragma unroll
            for (int cc = 0; cc < 4; ++cc) {
                float4 wv = wrow[cc];
                acc[cc].x += af0 * wv.x; acc[cc].y += af0 * wv.y;
                acc[cc].z += af0 * wv.z; acc[cc].w += af0 * wv.w;
            }
        }
    }
    #pragma unroll
    for (int cc = 0; cc < 4; ++cc) {
        float4 ov;
        ov.x = fsig(acc[cc].x);
        ov.y = fsig(acc[cc].y);
        ov.z = fsig(acc[cc].z);
        ov.w = fsig(acc[cc].w);
        *(float4*)(out + (size_t)r0 * HIDN + u0 + cc * 4) = ov;
    }
}

// ---------------------------------------------------------------------------
// Cooperative mega-kernel: 512 blocks x 512 thr, guaranteed 2 blocks/CU
// (launch_bounds(512,4) caps VGPR at 128; 64 KB arena -> 2 fit in 160 KB).
// P1: conv+z (blocks 0-127) || A-scan (128-511, 5-6 rows/wave)
// P2: LSTM (blocks 0-3)     || gather (4-511, 4-5 rows/wave)
// P3: outmm (blocks 0-255)
// ---------------------------------------------------------------------------
__global__ __launch_bounds__(NTHR, 4) void k_fused(
        const float* __restrict__ x, const float* __restrict__ A,
        const float* __restrict__ conv_w, const float* __restrict__ conv_b,
        const float* __restrict__ w_ih, const float* __restrict__ w_hh,
        const float* __restrict__ b_ih, const float* __restrict__ b_hh,
        float* __restrict__ z3, float* __restrict__ d_inv,
        int* __restrict__ cnt, int* __restrict__ idx,
        float* __restrict__ lw, float* __restrict__ agg,
        float* __restrict__ out) {
    __shared__ __align__(16) char arena[65536];
    cg::grid_group grid = cg::this_grid();
    const int tid = threadIdx.x;
    const int bid = blockIdx.x;
    const int wid = tid >> 6;
    const int lane = tid & 63;

    // ---- P1: conv+z || A-scan ----
    if (bid < 128) {
        convz_body(bid, tid, x, conv_w, conv_b, w_ih, b_ih, b_hh, z3, (float*)arena);
    } else {
        int* sidx_w = (int*)arena + wid * MAXNZ;
        const int gw = (bid - 128) * 8 + wid;      // 0..3071
        for (int r = gw; r < 16384; r += 3072)
            ascan_row(r, lane, A, d_inv, cnt, idx, sidx_w);
    }
    __threadfence();
    grid.sync();

    // ---- P2: LSTM || gather ----
    if (bid < 4) {
        lstm_body(bid, tid, z3, w_hh, lw, (float4*)arena, (_Float16*)(arena + 32768));
    } else {
        const int gw = (bid - 4) * 8 + wid;        // 0..4063
        for (int r = gw; r < 16384; r += 4064)
            gather_row(r, lane, x, d_inv, cnt, idx, agg);
    }
    __threadfence();
    grid.sync();

    // ---- P3: outmm ----
    if (bid < 256)
        outmm_body(bid, tid, agg, lw, out, (float*)arena);
}

// ---------------------------------------------------------------------------
// Fallback path (round-2 structure, built from the same bodies) — used only
// if the cooperative launch is rejected by the runtime/capture.
// ---------------------------------------------------------------------------
__global__ __launch_bounds__(512) void k1_fb(
        const float* __restrict__ x, const float* __restrict__ conv_w,
        const float* __restrict__ conv_b, const float* __restrict__ w_ih,
        const float* __restrict__ b_ih, const float* __restrict__ b_hh,
        float* __restrict__ z3,
        const float* __restrict__ A, float* __restrict__ d_inv,
        int* __restrict__ cnt, int* __restrict__ idx) {
    __shared__ __align__(16) char arena[4096];
    if (blockIdx.x < 128) {
        convz_body(blockIdx.x, threadIdx.x, x, conv_w, conv_b, w_ih, b_ih, b_hh,
                   z3, (float*)arena);
    } else {
        const int wid = threadIdx.x >> 6;
        const int lane = threadIdx.x & 63;
        int* sidx_w = (int*)arena + wid * MAXNZ;
        ascan_row((blockIdx.x - 128) * 8 + wid, lane, A, d_inv, cnt, idx, sidx_w);
    }
}

__global__ __launch_bounds__(512) void k2_fb(
        const float* __restrict__ z3, const float* __restrict__ w_hh,
        float* __restrict__ lw,
        const float* __restrict__ x, const float* __restrict__ d_inv,
        const int* __restrict__ cnt, const int* __restrict__ idx,
        float* __restrict__ agg) {
    __shared__ __align__(16) char arena[33280];
    if (blockIdx.x < 4) {
        lstm_body(blockIdx.x, threadIdx.x, z3, w_hh, lw,
                  (float4*)arena, (_Float16*)(arena + 32768));
    } else {
        const int wid = threadIdx.x >> 6;
        const int lane = threadIdx.x & 63;
        gather_row((blockIdx.x - 4) * 8 + wid, lane, x, d_inv, cnt, idx, agg);
    }
}

__global__ __launch_bounds__(512) void k3_fb(
        const float* __restrict__ agg, const float* __restrict__ lw,
        float* __restrict__ out) {
    __shared__ __align__(16) char arena[65536];
    outmm_body(blockIdx.x, threadIdx.x, agg, lw, out, (float*)arena);
}

// ---------------------------------------------------------------------------
extern "C" void kernel_launch(void* const* d_in, const int* in_sizes, int n_in,
                              void* d_out, int out_size, void* d_ws, size_t ws_size,
                              hipStream_t stream) {
    const float* x      = (const float*)d_in[0];
    const float* A      = (const float*)d_in[1];
    const float* conv_w = (const float*)d_in[2];
    const float* conv_b = (const float*)d_in[3];
    const float* w_ih   = (const float*)d_in[4];
    const float* w_hh   = (const float*)d_in[5];
    const float* b_ih   = (const float*)d_in[6];
    const float* b_hh   = (const float*)d_in[7];
    float* out = (float*)d_out;

    char* ws = (char*)d_ws;
    float* d_inv = (float*)ws;                                   // 64 KB
    int*   cnt   = (int*)(ws + 65536);                           // 64 KB
    int*   idx   = (int*)(ws + 131072);                          // 8 MB
    float* z3    = (float*)(ws + 131072 + 8388608);              // 1 MB
    float* lw    = (float*)(ws + 131072 + 8388608 + 1048576);    // 256 KB
    float* agg   = (float*)(ws + 131072 + 8388608 + 1048576 + 262144); // 8 MB

    void* args[] = {
        (void*)&x, (void*)&A, (void*)&conv_w, (void*)&conv_b,
        (void*)&w_ih, (void*)&w_hh, (void*)&b_ih, (void*)&b_hh,
        (void*)&z3, (void*)&d_inv, (void*)&cnt, (void*)&idx,
        (void*)&lw, (void*)&agg, (void*)&out,
    };
    hipError_t err = hipLaunchCooperativeKernel(
        (const void*)k_fused, dim3(CGRID), dim3(NTHR), (void**)args, 0, stream);
    if (err != hipSuccess) {
        // Fallback: plain 3-kernel pipeline (round-2 structure).
        hipLaunchKernelGGL(k1_fb, dim3(2176), dim3(512), 0, stream,
                           x, conv_w, conv_b, w_ih, b_ih, b_hh, z3, A, d_inv, cnt, idx);
        hipLaunchKernelGGL(k2_fb, dim3(2052), dim3(512), 0, stream,
                           z3, w_hh, lw, x, d_inv, cnt, idx, agg);
        hipLaunchKernelGGL(k3_fb, dim3(256), dim3(512), 0, stream, agg, lw, out);
    }
}

// Round 6
// 500.576 us; speedup vs baseline: 1.6780x; 1.6780x over previous
//
#include <hip/hip_runtime.h>
#include <hip/hip_cooperative_groups.h>
#include <math.h>

namespace cg = cooperative_groups;

#define N_NODES 4096
#define HIDN 128
#define MAXNZ 128
#define CGRID 512
#define NTHR 512

typedef float v4f __attribute__((ext_vector_type(4)));
typedef _Float16 h2 __attribute__((ext_vector_type(2)));
typedef _Float16 h8 __attribute__((ext_vector_type(8)));

__device__ __forceinline__ float fsig(float x) { return 1.0f / (1.0f + __expf(-x)); }
__device__ __forceinline__ float ftanh_(float x) { return 1.0f - 2.0f / (__expf(2.0f * x) + 1.0f); }

// ---------------------------------------------------------------------------
// Phase bodies (shared between the cooperative mega-kernel and the fallback
// 3-kernel path). LDS is passed as pointers into a per-kernel arena.
// ---------------------------------------------------------------------------

// conv1d + z precompute for one conv-block cb in [0,128). Needs 2 KB LDS (dl).
__device__ __forceinline__ void convz_body(
        int cb, int tid, const float* __restrict__ x,
        const float* __restrict__ conv_w, const float* __restrict__ conv_b,
        const float* __restrict__ w_ih, const float* __restrict__ b_ih,
        const float* __restrict__ b_hh, float* __restrict__ z3,
        float* dl /* 4*128 floats */) {
    const int b = cb >> 5;
    const int t0 = (cb & 31) * 4;
    const int tsub = tid >> 7;
    const int h = tid & 127;
    const int t = t0 + tsub;                       // timestep 0..127
    {
        const float* xb = x + ((size_t)b * N_NODES + (N_NODES - HIDN)) * HIDN;
        const float* w = conv_w + (size_t)t * HIDN * 3;
        float a0 = conv_b[t], a1 = 0.0f, a2 = 0.0f, a3 = 0.0f;
        #pragma unroll 4
        for (int i = 0; i < HIDN; i += 4) {
            const float* xr0 = xb + (size_t)i * HIDN;
            #pragma unroll
            for (int s = 0; s < 4; ++s) {
                const float* xr = xr0 + s * HIDN;
                float w0 = w[(i + s) * 3 + 0], w1 = w[(i + s) * 3 + 1], w2 = w[(i + s) * 3 + 2];
                float left  = (h > 0)   ? xr[h - 1] : 0.0f;
                float mid   = xr[h];
                float right = (h < 127) ? xr[h + 1] : 0.0f;
                if (s == 0)      a0 += left * w0 + mid * w1 + right * w2;
                else if (s == 1) a1 += left * w0 + mid * w1 + right * w2;
                else if (s == 2) a2 += left * w0 + mid * w1 + right * w2;
                else             a3 += left * w0 + mid * w1 + right * w2;
            }
        }
        dl[tsub * HIDN + h] = (a0 + a1) + (a2 + a3);
    }
    __syncthreads();
    // ---- z phase: thread = u = gate*128 + cell; 4 timesteps per thread ----
    const int u = tid;
    const int qg = u >> 7;                         // gate
    const int m  = u & 127;                        // cell
    const float4* wr = (const float4*)(w_ih + (size_t)u * HIDN);
    float bias = b_ih[u] + b_hh[u];
    float acc0 = bias, acc1 = bias, acc2 = bias, acc3 = bias;
    #pragma unroll
    for (int half = 0; half < 2; ++half) {
        float4 wv[16];
        #pragma unroll
        for (int j = 0; j < 16; ++j) wv[j] = wr[half * 16 + j];
        const float4* d0 = (const float4*)(dl + 0 * HIDN) + half * 16;
        const float4* d1 = (const float4*)(dl + 1 * HIDN) + half * 16;
        const float4* d2 = (const float4*)(dl + 2 * HIDN) + half * 16;
        const float4* d3 = (const float4*)(dl + 3 * HIDN) + half * 16;
        #pragma unroll
        for (int j = 0; j < 16; ++j) {
            float4 wj = wv[j];
            float4 v0 = d0[j], v1 = d1[j], v2 = d2[j], v3 = d3[j];
            acc0 += wj.x * v0.x + wj.y * v0.y + wj.z * v0.z + wj.w * v0.w;
            acc1 += wj.x * v1.x + wj.y * v1.y + wj.z * v1.z + wj.w * v1.w;
            acc2 += wj.x * v2.x + wj.y * v2.y + wj.z * v2.z + wj.w * v2.w;
            acc3 += wj.x * v3.x + wj.y * v3.y + wj.z * v3.z + wj.w * v3.w;
        }
    }
    float* zb = z3 + (size_t)b * HIDN * HIDN * 4;
    zb[((size_t)(t0 + 0) * 128 + m) * 4 + qg] = acc0;
    zb[((size_t)(t0 + 1) * 128 + m) * 4 + qg] = acc1;
    zb[((size_t)(t0 + 2) * 128 + m) * 4 + qg] = acc2;
    zb[((size_t)(t0 + 3) * 128 + m) * 4 + qg] = acc3;
}

// A-scan of one row r by one wave. sidx_w = 128 ints of LDS private to wave.
__device__ __forceinline__ void ascan_row(
        int r, int lane, const float* __restrict__ A, float* __restrict__ d_inv,
        int* __restrict__ cnt, int* __restrict__ idx, int* sidx_w) {
    const v4f* row = (const v4f*)(A + (size_t)r * N_NODES);
    const unsigned long long below = (1ull << lane) - 1ull;
    int cbase = 0;
    v4f cur[4], nxt[4];
    #pragma unroll
    for (int j = 0; j < 4; ++j) cur[j] = row[j * 64 + lane];
#define PROC1(c, col)                                                         \
    {                                                                         \
        bool nz = ((c) != 0.0f);                                              \
        unsigned long long mm = __ballot(nz);                                 \
        if (mm) {                                                             \
            if (nz) {                                                         \
                int p_ = cbase + __popcll(mm & below);                        \
                if (p_ < MAXNZ) sidx_w[p_] = (col);                           \
            }                                                                 \
            cbase += __popcll(mm);                                            \
        }                                                                     \
    }
    #pragma unroll
    for (int g = 0; g < 4; ++g) {
        if (g < 3) {
            #pragma unroll
            for (int j = 0; j < 4; ++j) nxt[j] = row[(g + 1) * 256 + j * 64 + lane];
        }
        #pragma unroll
        for (int j = 0; j < 4; ++j) {
            int col0 = ((g * 4 + j) * 64 + lane) * 4;
            PROC1(cur[j].x, col0 + 0);
            PROC1(cur[j].y, col0 + 1);
            PROC1(cur[j].z, col0 + 2);
            PROC1(cur[j].w, col0 + 3);
        }
        #pragma unroll
        for (int j = 0; j < 4; ++j) cur[j] = nxt[j];
    }
#undef PROC1
    int cnt_r = (cbase < MAXNZ) ? cbase : MAXNZ;
    for (int k = lane; k < cnt_r; k += 64)
        idx[r * MAXNZ + k] = sidx_w[k];
    if (lane == 0) {
        cnt[r] = cnt_r;
        d_inv[r] = rsqrtf((float)(cbase + 1));
    }
}

// LSTM for batch b, full 512-thread block. zl = 32 KB, hb = 512 B of LDS.
// thread = (cell m = t>>2, k-quarter q = t&3); w2 = 64 VGPR of f16 weights,
// H0-H3 = 16 VGPR h-quarter, total ~105-115 VGPR demand. MUST get a
// >=112-VGPR allocation or the weights spill into the serial 128-step loop
// (round 3: allocator chose the 64-VGPR/8-wave tier and spilled -> 589 us).
// The enclosing kernels pin amdgpu_waves_per_eu(4,4): budget exactly 128
// VGPR, allocator has no incentive to spill down to a higher-wave tier.
__device__ __forceinline__ void lstm_body(
        int b, int t, const float* __restrict__ z3, const float* __restrict__ w_hh,
        float* __restrict__ lw, float4* zl, _Float16* hb) {
    const int m = t >> 2;                          // cell 0..127
    const int q = t & 3;                           // k-quarter 0..3
    h2 w2[4][16];
    #pragma unroll
    for (int g = 0; g < 4; ++g) {
        const float4* wr = (const float4*)(w_hh + ((size_t)(g * HIDN + m)) * HIDN + q * 32);
        #pragma unroll
        for (int j4 = 0; j4 < 8; ++j4) {
            float4 wv = wr[j4];
            w2[g][2 * j4 + 0] = h2{(_Float16)wv.x, (_Float16)wv.y};
            w2[g][2 * j4 + 1] = h2{(_Float16)wv.z, (_Float16)wv.w};
        }
    }
    float c = 0.0f;
    if (t < 64) ((h2*)hb)[t] = h2{(_Float16)0.0f, (_Float16)0.0f};
    const float4* zsrc = (const float4*)z3 + (size_t)b * 16384;
    float* lwb = lw + (size_t)b * HIDN * HIDN + m;
    float hist[4];
    for (int ch = 0; ch < 8; ++ch) {
        // ---- stage chunk (all 8 waves): 32 KB straight copy ----
        const float4* src = zsrc + ch * 2048;
        #pragma unroll
        for (int k = 0; k < 4; ++k)
            zl[t + 512 * k] = src[t + 512 * k];
        __syncthreads();
        #pragma unroll
        for (int si = 0; si < 16; ++si) {
            const int s = ch * 16 + si;
            const h8* hp = ((const h8*)(hb + (size_t)(s & 1) * HIDN)) + q * 4;
            h8 H0 = hp[0], H1 = hp[1], H2 = hp[2], H3 = hp[3];
            float4 zv = zl[si * 128 + m];          // broadcast b128
            float a0 = 0.f, a1 = 0.f, a2 = 0.f, a3 = 0.f;
            #pragma unroll
            for (int j = 0; j < 16; ++j) {
                h2 hj = (j < 4)  ? ((const h2*)&H0)[j]
                      : (j < 8)  ? ((const h2*)&H1)[j - 4]
                      : (j < 12) ? ((const h2*)&H2)[j - 8]
                                 : ((const h2*)&H3)[j - 12];
                a0 = __builtin_amdgcn_fdot2(w2[0][j], hj, a0, false);
                a1 = __builtin_amdgcn_fdot2(w2[1][j], hj, a1, false);
                a2 = __builtin_amdgcn_fdot2(w2[2][j], hj, a2, false);
                a3 = __builtin_amdgcn_fdot2(w2[3][j], hj, a3, false);
            }
            // butterfly across the 4 k-quarters (lanes t^1, t^2)
            a0 += __shfl_xor(a0, 1); a0 += __shfl_xor(a0, 2);
            a1 += __shfl_xor(a1, 1); a1 += __shfl_xor(a1, 2);
            a2 += __shfl_xor(a2, 1); a2 += __shfl_xor(a2, 2);
            a3 += __shfl_xor(a3, 1); a3 += __shfl_xor(a3, 2);
            float zi = a0 + zv.x;
            float zf = a1 + zv.y;
            float zg = a2 + zv.z;
            float zo = a3 + zv.w;
            float ig = fsig(zi);
            float fg = fsig(zf);
            float gg = ftanh_(zg);
            float og = fsig(zo);
            c = fg * c + ig * gg;                  // identical in all 4 quartet lanes
            float hn = og * ftanh_(c);
            if (q == (si & 3)) hist[si >> 2] = hn; // each quartet lane keeps 4 steps
            if (q == 0) hb[(size_t)((s + 1) & 1) * HIDN + m] = (_Float16)hn;
            __syncthreads();
        }
        // chunk-end lw store (f32, full precision), coalesced per q-group
        #pragma unroll
        for (int j = 0; j < 4; ++j)
            lwb[(size_t)(ch * 16 + q + 4 * j) * HIDN] = hist[j];
    }
}

// gather of one row r by one wave; d_inv read from global (L1/L2-resident,
// 16 KB per batch) so no LDS staging is needed.
__device__ __forceinline__ void gather_row(
        int r, int lane, const float* __restrict__ x,
        const float* __restrict__ d_inv, const int* __restrict__ cnt,
        const int* __restrict__ idx, float* __restrict__ agg) {
    const int b = r >> 12;
    const int i = r & 4095;
    const float* dv = d_inv + (b << 12);
    const float2* xb = (const float2*)(x + (size_t)b * N_NODES * HIDN);
    const int* irow = idx + r * MAXNZ;
    const int n = cnt[r];
    float ax = 0.0f, ay = 0.0f;
    int k = 0;
    for (; k + 8 <= n; k += 8) {
        int4 j0 = *(const int4*)&irow[k];
        int4 j1 = *(const int4*)&irow[k + 4];
        float2 v0 = xb[(size_t)j0.x * 64 + lane];
        float2 v1 = xb[(size_t)j0.y * 64 + lane];
        float2 v2 = xb[(size_t)j0.z * 64 + lane];
        float2 v3 = xb[(size_t)j0.w * 64 + lane];
        float2 v4 = xb[(size_t)j1.x * 64 + lane];
        float2 v5 = xb[(size_t)j1.y * 64 + lane];
        float2 v6 = xb[(size_t)j1.z * 64 + lane];
        float2 v7 = xb[(size_t)j1.w * 64 + lane];
        float d0 = dv[j0.x], d1 = dv[j0.y], d2 = dv[j0.z], d3 = dv[j0.w];
        float d4 = dv[j1.x], d5 = dv[j1.y], d6 = dv[j1.z], d7 = dv[j1.w];
        ax += d0 * v0.x + d1 * v1.x + d2 * v2.x + d3 * v3.x
            + d4 * v4.x + d5 * v5.x + d6 * v6.x + d7 * v7.x;
        ay += d0 * v0.y + d1 * v1.y + d2 * v2.y + d3 * v3.y
            + d4 * v4.y + d5 * v5.y + d6 * v6.y + d7 * v7.y;
    }
    for (; k < n; ++k) {
        int j = irow[k];
        float dj = dv[j];
        float2 v = xb[(size_t)j * 64 + lane];
        ax += dj * v.x;
        ay += dj * v.y;
    }
    float di = dv[i];
    float2 vi = xb[(size_t)i * 64 + lane];
    float2 o2;
    o2.x = di * (ax + di * vi.x);
    o2.y = di * (ay + di * vi.y);
    ((float2*)(agg + (size_t)r * HIDN))[lane] = o2;
}

// outmm for block bb in [0,512): 32 rows, 512 threads = 32 rows x 16 col-thr.
// Each thread: 8 cols as 2 float4 at STRIDE-64 floats (u0=(tid&15)*4,
// cc*64). Distinct LDS addresses per wave: 16 x 16B spanning 256 B -> all
// 32 banks 2-way (free, m136); repeats are same-address broadcast. The old
// (tid&7)*16 partition aliased mod 128 B -> 4-way conflict, 4.19M
// SQ_LDS_BANK_CONFLICT (round 3). lw_lds = 64 KB LDS.
__device__ __forceinline__ void outmm_body(
        int bb, int tid, const float* __restrict__ agg,
        const float* __restrict__ lw, float* __restrict__ out, float* lw_lds) {
    const int i0 = bb * 32;
    const int b = i0 >> 12;
    const float4* lwg = (const float4*)(lw + (size_t)b * HIDN * HIDN);
    float4* lds4 = (float4*)lw_lds;
    for (int v = tid; v < HIDN * HIDN / 4; v += NTHR) lds4[v] = lwg[v];
    __syncthreads();
    const int r0 = i0 + (tid >> 4);
    const int u0 = (tid & 15) * 4;
    const float4* a4 = (const float4*)agg;
    float4 acc[2];
    acc[0] = make_float4(0.f, 0.f, 0.f, 0.f);
    acc[1] = make_float4(0.f, 0.f, 0.f, 0.f);
    for (int f4 = 0; f4 < 32; ++f4) {
        float4 a0 = a4[(size_t)r0 * 32 + f4];
        #pragma unroll
        for (int ff = 0; ff < 4; ++ff) {
            float af0 = (ff == 0) ? a0.x : (ff == 1) ? a0.y : (ff == 2) ? a0.z : a0.w;
            const float* wrow = lw_lds + (f4 * 4 + ff) * HIDN + u0;
            #pragma unroll
            for (int cc = 0; cc < 2; ++cc) {
                float4 wv = *(const float4*)(wrow + cc * 64);
                acc[cc].x += af0 * wv.x; acc[cc].y += af0 * wv.y;
                acc[cc].z += af0 * wv.z; acc[cc].w += af0 * wv.w;
            }
        }
    }
    #pragma unroll
    for (int cc = 0; cc < 2; ++cc) {
        float4 ov;
        ov.x = fsig(acc[cc].x);
        ov.y = fsig(acc[cc].y);
        ov.z = fsig(acc[cc].z);
        ov.w = fsig(acc[cc].w);
        *(float4*)(out + (size_t)r0 * HIDN + u0 + cc * 64) = ov;
    }
}

// ---------------------------------------------------------------------------
// Cooperative mega-kernel: 512 blocks x 512 thr = 2 blocks/CU.
// amdgpu_waves_per_eu(4,4) pins the allocator to the 4-wave/EU tier:
// VGPR budget exactly 128 (LSTM's ~110 fits, NO spill) and no incentive to
// spill down to 64 VGPR for 8 waves (round 3's failure mode). 2 blocks/CU
// (LDS 2x64KB <= 160KB) => 512 co-resident blocks. The HOST gates the
// cooperative launch on an occupancy query, so if the compiler ever breaks
// this arithmetic we take the fallback instead of deadlocking grid.sync().
// P1: conv+z (blocks 0-127) || A-scan (128-511, 5-6 rows/wave)
// P2: LSTM (blocks 0-3)     || gather (4-511, ~4 rows/wave)
// P3: outmm (all 512 blocks, 32 rows each)
// ---------------------------------------------------------------------------
__global__ __launch_bounds__(NTHR)
__attribute__((amdgpu_waves_per_eu(4, 4)))
void k_fused(
        const float* __restrict__ x, const float* __restrict__ A,
        const float* __restrict__ conv_w, const float* __restrict__ conv_b,
        const float* __restrict__ w_ih, const float* __restrict__ w_hh,
        const float* __restrict__ b_ih, const float* __restrict__ b_hh,
        float* __restrict__ z3, float* __restrict__ d_inv,
        int* __restrict__ cnt, int* __restrict__ idx,
        float* __restrict__ lw, float* __restrict__ agg,
        float* __restrict__ out) {
    __shared__ __align__(16) char arena[65536];
    cg::grid_group grid = cg::this_grid();
    const int tid = threadIdx.x;
    const int bid = blockIdx.x;
    const int wid = tid >> 6;
    const int lane = tid & 63;

    // ---- P1: conv+z || A-scan ----
    if (bid < 128) {
        convz_body(bid, tid, x, conv_w, conv_b, w_ih, b_ih, b_hh, z3, (float*)arena);
    } else {
        int* sidx_w = (int*)arena + wid * MAXNZ;
        const int gw = (bid - 128) * 8 + wid;      // 0..3071
        for (int r = gw; r < 16384; r += 3072)
            ascan_row(r, lane, A, d_inv, cnt, idx, sidx_w);
    }
    __threadfence();
    grid.sync();

    // ---- P2: LSTM || gather ----
    if (bid < 4) {
        lstm_body(bid, tid, z3, w_hh, lw, (float4*)arena, (_Float16*)(arena + 32768));
    } else {
        const int gw = (bid - 4) * 8 + wid;        // 0..4063
        for (int r = gw; r < 16384; r += 4064)
            gather_row(r, lane, x, d_inv, cnt, idx, agg);
    }
    __threadfence();
    grid.sync();

    // ---- P3: outmm ----
    outmm_body(bid, tid, agg, lw, out, (float*)arena);
}

// ---------------------------------------------------------------------------
// Fallback path (round-2 structure, built from the same bodies) — used when
// the occupancy query says the cooperative grid cannot co-reside, or the
// cooperative launch errors.
// ---------------------------------------------------------------------------
__global__ __launch_bounds__(512) void k1_fb(
        const float* __restrict__ x, const float* __restrict__ conv_w,
        const float* __restrict__ conv_b, const float* __restrict__ w_ih,
        const float* __restrict__ b_ih, const float* __restrict__ b_hh,
        float* __restrict__ z3,
        const float* __restrict__ A, float* __restrict__ d_inv,
        int* __restrict__ cnt, int* __restrict__ idx) {
    __shared__ __align__(16) char arena[4096];
    if (blockIdx.x < 128) {
        convz_body(blockIdx.x, threadIdx.x, x, conv_w, conv_b, w_ih, b_ih, b_hh,
                   z3, (float*)arena);
    } else {
        const int wid = threadIdx.x >> 6;
        const int lane = threadIdx.x & 63;
        int* sidx_w = (int*)arena + wid * MAXNZ;
        ascan_row((blockIdx.x - 128) * 8 + wid, lane, A, d_inv, cnt, idx, sidx_w);
    }
}

__global__ __launch_bounds__(512)
__attribute__((amdgpu_waves_per_eu(4, 4)))
void k2_fb(
        const float* __restrict__ z3, const float* __restrict__ w_hh,
        float* __restrict__ lw,
        const float* __restrict__ x, const float* __restrict__ d_inv,
        const int* __restrict__ cnt, const int* __restrict__ idx,
        float* __restrict__ agg) {
    __shared__ __align__(16) char arena[33280];
    if (blockIdx.x < 4) {
        lstm_body(blockIdx.x, threadIdx.x, z3, w_hh, lw,
                  (float4*)arena, (_Float16*)(arena + 32768));
    } else {
        const int wid = threadIdx.x >> 6;
        const int lane = threadIdx.x & 63;
        gather_row((blockIdx.x - 4) * 8 + wid, lane, x, d_inv, cnt, idx, agg);
    }
}

__global__ __launch_bounds__(512) void k3_fb(
        const float* __restrict__ agg, const float* __restrict__ lw,
        float* __restrict__ out) {
    __shared__ __align__(16) char arena[65536];
    outmm_body(blockIdx.x, threadIdx.x, agg, lw, out, (float*)arena);
}

// ---------------------------------------------------------------------------
extern "C" void kernel_launch(void* const* d_in, const int* in_sizes, int n_in,
                              void* d_out, int out_size, void* d_ws, size_t ws_size,
                              hipStream_t stream) {
    const float* x      = (const float*)d_in[0];
    const float* A      = (const float*)d_in[1];
    const float* conv_w = (const float*)d_in[2];
    const float* conv_b = (const float*)d_in[3];
    const float* w_ih   = (const float*)d_in[4];
    const float* w_hh   = (const float*)d_in[5];
    const float* b_ih   = (const float*)d_in[6];
    const float* b_hh   = (const float*)d_in[7];
    float* out = (float*)d_out;

    char* ws = (char*)d_ws;
    float* d_inv = (float*)ws;                                   // 64 KB
    int*   cnt   = (int*)(ws + 65536);                           // 64 KB
    int*   idx   = (int*)(ws + 131072);                          // 8 MB
    float* z3    = (float*)(ws + 131072 + 8388608);              // 1 MB
    float* lw    = (float*)(ws + 131072 + 8388608 + 1048576);    // 256 KB
    float* agg   = (float*)(ws + 131072 + 8388608 + 1048576 + 262144); // 8 MB

    // Provable co-residency gate (host-side query; no stream ops, safe under
    // graph capture). 256 CUs on MI355X; need all CGRID blocks resident.
    static int coop_ok = -1;
    if (coop_ok < 0) {
        int nb = 0;
        hipError_t qerr = hipOccupancyMaxActiveBlocksPerMultiprocessor(
            &nb, (const void*)k_fused, NTHR, 0);
        coop_ok = (qerr == hipSuccess && nb * 256 >= CGRID) ? 1 : 0;
    }

    if (coop_ok == 1) {
        void* args[] = {
            (void*)&x, (void*)&A, (void*)&conv_w, (void*)&conv_b,
            (void*)&w_ih, (void*)&w_hh, (void*)&b_ih, (void*)&b_hh,
            (void*)&z3, (void*)&d_inv, (void*)&cnt, (void*)&idx,
            (void*)&lw, (void*)&agg, (void*)&out,
        };
        hipError_t err = hipLaunchCooperativeKernel(
            (const void*)k_fused, dim3(CGRID), dim3(NTHR), (void**)args, 0, stream);
        if (err == hipSuccess) return;
        coop_ok = 0;  // don't retry a failing path
    }

    // Fallback: plain 3-kernel pipeline (round-2 structure).
    hipLaunchKernelGGL(k1_fb, dim3(2176), dim3(512), 0, stream,
                       x, conv_w, conv_b, w_ih, b_ih, b_hh, z3, A, d_inv, cnt, idx);
    hipLaunchKernelGGL(k2_fb, dim3(2052), dim3(512), 0, stream,
                       z3, w_hh, lw, x, d_inv, cnt, idx, agg);
    hipLaunchKernelGGL(k3_fb, dim3(512), dim3(512), 0, stream, agg, lw, out);
}